// Round 10
// baseline (47.764 us; speedup 1.0000x reference)
//
#include <hip/hip_runtime.h>

#define S 256
#define NF 4096
#define TILE 16
#define HTILE 8            // half-tile: 16 wide x 8 tall
#define NLISTS 512         // 16 x 32 half-tiles
#define CAPC 256           // record slots per half-tile (avg ~30; overflow -> exact fallback)
#define NT 1024            // render: 8 slices x 128 pixels
#define SLICES 8
#define NEARF 0.1f
#define FARF 100.0f
#define EPSF 1e-8f

// ws layout: [0, 2048)        count[512] (int)
//            [4096, 4096+8MB) rec[512][CAPC][4] (float4, 64B/slot)
#define WS_REC_OFF 4096

// ---- Kernel A: bin all faces into half-tile lists (one pass over the scene;
// replaces 512 redundant per-block culls = ~226MB/launch of L2 streaming). ----
__global__ __launch_bounds__(64) void bin_faces(const float* __restrict__ faces,
                                                int* __restrict__ count,
                                                float4* __restrict__ rec) {
    const int f = blockIdx.x * 64 + (int)threadIdx.x;   // 64 blocks x 64 = 4096
    const float* p = faces + (size_t)f * 9;
    const float4 A = *(const float4*)p;        // x0,y0,z0,x1
    const float4 B = *(const float4*)(p + 4);  // y1,z1,x2,y2
    const float z2 = p[8];
    const float x0 = A.x, y0 = A.y, x1 = A.w;
    const float y1 = B.x, x2 = B.z, y2 = B.w;

    // Backface cull, fp32 conservative (|err| < 1.5e-6 << 1e-4 margin; proven R7/R8).
    const float a2 = __fsub_rn(__fmul_rn(__fsub_rn(x1, x0), __fsub_rn(y2, y0)),
                               __fmul_rn(__fsub_rn(x2, x0), __fsub_rn(y1, y0)));
    if (a2 <= -1e-4f) return;

    // Conservative pixel range from bbox (+-1e-3 NDC margin, +-1px slack; proven R3).
    const float bxmin = fminf(x0, fminf(x1, x2)) - 1e-3f;
    const float bxmax = fmaxf(x0, fmaxf(x1, x2)) + 1e-3f;
    const float bymin = fminf(y0, fminf(y1, y2)) - 1e-3f;
    const float bymax = fmaxf(y0, fmaxf(y1, y2)) + 1e-3f;
    int pxlo = (int)ceilf((256.0f * bxmin + 255.0f) * 0.5f) - 1;
    int pxhi = (int)floorf((256.0f * bxmax + 255.0f) * 0.5f) + 1;
    int pylo = (int)ceilf((256.0f * bymin + 255.0f) * 0.5f) - 1;
    int pyhi = (int)floorf((256.0f * bymax + 255.0f) * 0.5f) + 1;
    if (pxhi < 0 || pxlo > S - 1 || pyhi < 0 || pylo > S - 1) return;
    pxlo = pxlo < 0 ? 0 : pxlo;
    pylo = pylo < 0 ? 0 : pylo;
    pxhi = pxhi > S - 1 ? S - 1 : pxhi;
    pyhi = pyhi > S - 1 ? S - 1 : pyhi;

    // Edge deltas: identical __fsub_rn ops to the reference's per-pixel values.
    const float dx21 = __fsub_rn(x2, x1), dy21 = __fsub_rn(y2, y1);
    const float dx02 = __fsub_rn(x0, x2), dy02 = __fsub_rn(y0, y2);
    const float dx10 = __fsub_rn(x1, x0), dy10 = __fsub_rn(y1, y0);
    const float4 r2 = make_float4(z2, __int_as_float(f), dx21, dy21);
    const float4 r3 = make_float4(dx02, dy02, dx10, dy10);

    for (int hy = pylo >> 3; hy <= pyhi >> 3; ++hy)
        for (int hx = pxlo >> 4; hx <= pxhi >> 4; ++hx) {
            const int list = hy * 16 + hx;
            const int slot = atomicAdd(&count[list], 1);
            if (slot < CAPC) {
                float4* d = rec + ((size_t)list * CAPC + slot) * 4;
                d[0] = A;
                d[1] = B;
                d[2] = r2;
                d[3] = r3;
            }
        }
}

// ---- Kernel B: render (R8's proven shape: 512 blocks x 1024 thr, 8 slices x
// 128 px, 2 blocks/CU). Cull replaced by a coalesced LDS stage of the bins.
// Merge via (depth_bits<<32|face) min-key: order-independent, exact
// lowest-index tie-break -> bin scatter order is irrelevant. ----
__global__ __launch_bounds__(NT, 8) void render_half(const int* __restrict__ count,
                                                     const float4* __restrict__ rec,
                                                     const float* __restrict__ faces,
                                                     int* __restrict__ out) {
    __shared__ float4 s_cand[CAPC][4];          // 16 KB
    __shared__ unsigned long long s_key[NT];    // 8 KB

    const int bx = blockIdx.x;
    const int tile = bx & 255;
    const int half = bx >> 8;
    const int tx0 = (tile & (S / TILE - 1)) * TILE;
    const int ty0 = (tile / (S / TILE)) * TILE + half * HTILE;
    const int list = (ty0 >> 3) * 16 + (tx0 >> 4);

    const int nc = count[list];
    const int n = nc < CAPC ? nc : CAPC;

    // Coalesced stage: n*4 float4s (~2.5KB typical) global -> LDS.
    const float4* src = rec + (size_t)list * CAPC * 4;
    for (int k = threadIdx.x; k < n * 4; k += NT)
        ((float4*)s_cand)[k] = src[k];
    __syncthreads();

    const int pix = threadIdx.x & 127;           // 16 x 8 pixels
    const int slice = threadIdx.x >> 7;          // wave-uniform
    const int px = tx0 + (pix & (TILE - 1));
    const int py = ty0 + (pix >> 4);
    // (2i+1-256)/256: odd numerator / pow2 -> exact in fp32.
    const float xp = (2.0f * px + 1.0f - 256.0f) * (1.0f / 256.0f);
    const float yp = (2.0f * py + 1.0f - 256.0f) * (1.0f / 256.0f);

    float bestd = FARF;
    int bestf = 0x7fffffff;

    if (nc <= CAPC) {
        for (int i = slice; i < n; i += SLICES) {
            const float4 a = s_cand[i][0];   // broadcast reads, conflict-free
            const float4 b = s_cand[i][1];
            const float4 c = s_cand[i][2];
            const float4 d = s_cand[i][3];
            const float X0 = a.x, Y0 = a.y, Z0 = a.z, X1 = a.w;
            const float Y1 = b.x, Z1 = b.y, X2 = b.z, Y2 = b.w;
            const float Z2 = c.x;
            const int f = __float_as_int(c.y);
            const float w0 = __fsub_rn(__fmul_rn(__fsub_rn(yp, Y1), c.z),
                                       __fmul_rn(__fsub_rn(xp, X1), c.w));
            const float w1 = __fsub_rn(__fmul_rn(__fsub_rn(yp, Y2), d.x),
                                       __fmul_rn(__fsub_rn(xp, X2), d.y));
            const float w2 = __fsub_rn(__fmul_rn(__fsub_rn(yp, Y0), d.z),
                                       __fmul_rn(__fsub_rn(xp, X0), d.w));
            const bool inside = (__fmul_rn(w0, w1) > 0.0f) && (__fmul_rn(w1, w2) > 0.0f);
            const float wsum = __fadd_rn(__fadd_rn(w0, w1), w2);
            if (inside && (wsum > 0.0f)) {
                float denom = __fadd_rn(__fadd_rn(__fdiv_rn(w0, Z0), __fdiv_rn(w1, Z1)),
                                        __fdiv_rn(w2, Z2));
                denom = (fabsf(denom) > EPSF) ? denom : EPSF;
                const float zp = __fdiv_rn(wsum, denom);
                if ((zp > NEARF) && (zp < FARF)) {
                    if (zp < bestd || (zp == bestd && f < bestf)) {
                        bestd = zp;
                        bestf = f;
                    }
                }
            }
        }
    } else {
        // Overflow (never expected): test every face directly from global.
        // Conservative-cull equivalence keeps this exact.
        for (int i = slice; i < NF; i += SLICES) {
            const float* p = faces + (size_t)i * 9;
            const float X0 = p[0], Y0 = p[1], Z0 = p[2];
            const float X1 = p[3], Y1 = p[4], Z1 = p[5];
            const float X2 = p[6], Y2 = p[7], Z2 = p[8];
            const float w0 = __fsub_rn(__fmul_rn(__fsub_rn(yp, Y1), __fsub_rn(X2, X1)),
                                       __fmul_rn(__fsub_rn(xp, X1), __fsub_rn(Y2, Y1)));
            const float w1 = __fsub_rn(__fmul_rn(__fsub_rn(yp, Y2), __fsub_rn(X0, X2)),
                                       __fmul_rn(__fsub_rn(xp, X2), __fsub_rn(Y0, Y2)));
            const float w2 = __fsub_rn(__fmul_rn(__fsub_rn(yp, Y0), __fsub_rn(X1, X0)),
                                       __fmul_rn(__fsub_rn(xp, X0), __fsub_rn(Y1, Y0)));
            const bool inside = (__fmul_rn(w0, w1) > 0.0f) && (__fmul_rn(w1, w2) > 0.0f);
            const float wsum = __fadd_rn(__fadd_rn(w0, w1), w2);
            if (inside && (wsum > 0.0f)) {
                float denom = __fadd_rn(__fadd_rn(__fdiv_rn(w0, Z0), __fdiv_rn(w1, Z1)),
                                        __fdiv_rn(w2, Z2));
                denom = (fabsf(denom) > EPSF) ? denom : EPSF;
                const float zp = __fdiv_rn(wsum, denom);
                if ((zp > NEARF) && (zp < FARF)) {
                    if (zp < bestd || (zp == bestd && i < bestf)) {
                        bestd = zp;
                        bestf = i;
                    }
                }
            }
        }
    }

    // ---- merge 8 slices per pixel via packed min-key ----
    s_key[threadIdx.x] =
        ((unsigned long long)__float_as_uint(bestd) << 32) | (unsigned int)bestf;
    __syncthreads();
    if (threadIdx.x < 128) {
        unsigned long long k = s_key[threadIdx.x];
#pragma unroll
        for (int s = 1; s < SLICES; ++s) {
            const unsigned long long ks = s_key[threadIdx.x + 128 * s];
            k = ks < k ? ks : k;
        }
        const float dd = __uint_as_float((unsigned int)(k >> 32));
        const int fi = (int)(unsigned int)k;
        const int opx = tx0 + ((int)threadIdx.x & (TILE - 1));
        const int opy = ty0 + ((int)threadIdx.x >> 4);
        out[opy * S + opx] = (dd < FARF) ? fi : -1;
    }
}

extern "C" void kernel_launch(void* const* d_in, const int* in_sizes, int n_in,
                              void* d_out, int out_size, void* d_ws, size_t ws_size,
                              hipStream_t stream) {
    const float* faces = (const float*)d_in[0];
    int* out = (int*)d_out;
    int* count = (int*)d_ws;
    float4* rec = (float4*)((char*)d_ws + WS_REC_OFF);

    hipMemsetAsync(count, 0, NLISTS * sizeof(int), stream);
    hipLaunchKernelGGL(bin_faces, dim3(NF / 64), dim3(64), 0, stream,
                       faces, count, rec);
    hipLaunchKernelGGL(render_half, dim3(2 * (S / TILE) * (S / TILE)), dim3(NT), 0,
                       stream, count, rec, faces, out);
}

// Round 12
// 27.828 us; speedup vs baseline: 1.7164x; 1.7164x over previous
//
#include <hip/hip_runtime.h>

#define S 256
#define NF 4096
#define TILE 16
#define HTILE 8            // block region: 16 wide x 8 tall (two 16x4 quarter-regions)
#define NT 1024            // 16 waves: waves 0-7 -> region Q0, 8-15 -> Q1
#define SLICES 8
#define CAPC 256           // candidate slots per quarter-region list
#define NEARF 0.1f
#define FARF 100.0f
#define EPSF 1e-8f

// R8 structure (512 half-tile blocks, 2/CU, 32 waves/CU) with one change that
// the calibrated issue model says matters: each candidate body now runs on ONE
// wave instead of two. The half-tile's 128 px are split into two 16x4 regions
// with separate candidate lists (single shared cull tests both y-ranges; a face
// spanning both regions is recorded twice -- catch-area math says +70% records
// but bodies/candidate halve: net -15% wave-bodies, cull cost unchanged).
// Body micro-diet: inside&&facing == (w0>0 && w1>0 && w2>0) exactly (for
// DRAW_BACKSIDE=False; w=0 excluded both ways, |w|>=~1e-12 so no product
// underflow ambiguity), wsum computed only inside the predicated block.
// Merge via (depth_bits<<32|face) min-key: order-independent, exact
// lowest-index tie-break -> atomic list order irrelevant.
__global__ __launch_bounds__(NT, 8) void raster_tile(const float* __restrict__ faces,
                                                     int* __restrict__ out) {
    __shared__ float4 s_cand[2][CAPC][4];       // 32 KB
    __shared__ unsigned long long s_key[NT];    // 8 KB
    __shared__ int s_cnt[2];

    const int bx = blockIdx.x;
    const int tile = bx & 255;
    const int half = bx >> 8;
    const int tx0 = (tile & (S / TILE - 1)) * TILE;
    const int ty0 = (tile / (S / TILE)) * TILE + half * HTILE;

    // Region of this thread: waves 0-7 -> Q0 (rows 0-3), waves 8-15 -> Q1 (4-7).
    const int qr = (int)threadIdx.x >> 9;        // wave-uniform
    const int slice = ((int)threadIdx.x >> 6) & 7;
    const int lane = (int)threadIdx.x & 63;
    const int px = tx0 + (lane & (TILE - 1));
    const int py = ty0 + qr * 4 + (lane >> 4);
    // (2i+1-256)/256: odd numerator / pow2 -> exact in fp32.
    const float xp = (2.0f * px + 1.0f - 256.0f) * (1.0f / 256.0f);
    const float yp = (2.0f * py + 1.0f - 256.0f) * (1.0f / 256.0f);

    // Pixel-center bounds (x: full 16; y: per 4-row region) with 1e-5 margin
    // vs ulp-level boundary flips (proven conservative in R2..R8).
    const float cxlo = (2.0f * tx0 + 1.0f - 256.0f) * (1.0f / 256.0f) - 1e-5f;
    const float cxhi = (2.0f * (tx0 + TILE - 1) + 1.0f - 256.0f) * (1.0f / 256.0f) + 1e-5f;
    const float cylo0 = (2.0f * ty0 + 1.0f - 256.0f) * (1.0f / 256.0f) - 1e-5f;
    const float cyhi0 = (2.0f * (ty0 + 3) + 1.0f - 256.0f) * (1.0f / 256.0f) + 1e-5f;
    const float cylo1 = (2.0f * (ty0 + 4) + 1.0f - 256.0f) * (1.0f / 256.0f) - 1e-5f;
    const float cyhi1 = (2.0f * (ty0 + 7) + 1.0f - 256.0f) * (1.0f / 256.0f) + 1e-5f;

    // ---- cull: 4 faces/thread, all loads issued before any use ----
    float4 A[4], B[4];
    float Cz[4];
#pragma unroll
    for (int i = 0; i < 4; ++i) {
        const float* p = faces + (size_t)(i * NT + threadIdx.x) * 9;
        A[i] = *(const float4*)p;        // x0,y0,z0,x1
        B[i] = *(const float4*)(p + 4);  // y1,z1,x2,y2
        Cz[i] = p[8];                    // z2
    }
    if (threadIdx.x < 2) s_cnt[threadIdx.x] = 0;
    __syncthreads();   // sits under the global-load latency

#pragma unroll
    for (int i = 0; i < 4; ++i) {
        const float x0 = A[i].x, y0 = A[i].y, x1 = A[i].w;
        const float y1 = B[i].x, x2 = B[i].z, y2 = B[i].w;
        const float bxmin = fminf(x0, fminf(x1, x2));
        const float bxmax = fmaxf(x0, fmaxf(x1, x2));
        const float bymin = fminf(y0, fminf(y1, y2));
        const float bymax = fmaxf(y0, fmaxf(y1, y2));
        bool xok = (bxmax >= cxlo) && (bxmin <= cxhi);
        if (xok) {
            // 2*signed area fp32: |err| < 1.5e-6 << 1e-4 margin -> no pixel
            // whose fp32 w_sum>0 can be lost to this cull.
            const float a2 = __fsub_rn(
                __fmul_rn(__fsub_rn(x1, x0), __fsub_rn(y2, y0)),
                __fmul_rn(__fsub_rn(x2, x0), __fsub_rn(y1, y0)));
            xok = (a2 > -1e-4f);
        }
        const bool hit0 = xok && (bymax >= cylo0) && (bymin <= cyhi0);
        const bool hit1 = xok && (bymax >= cylo1) && (bymin <= cyhi1);
        if (hit0 || hit1) {
            // Edge deltas: identical __fsub_rn ops to the reference's
            // per-pixel values -> bit-identical, hoisted once per record.
            const float dx21 = __fsub_rn(x2, x1), dy21 = __fsub_rn(y2, y1);
            const float dx02 = __fsub_rn(x0, x2), dy02 = __fsub_rn(y0, y2);
            const float dx10 = __fsub_rn(x1, x0), dy10 = __fsub_rn(y1, y0);
            const int f = i * NT + (int)threadIdx.x;
            const float4 r2 = make_float4(Cz[i], __int_as_float(f), dx21, dy21);
            const float4 r3 = make_float4(dx02, dy02, dx10, dy10);
#pragma unroll
            for (int q = 0; q < 2; ++q) {
                if (q == 0 ? hit0 : hit1) {
                    const int slot = atomicAdd(&s_cnt[q], 1);
                    if (slot < CAPC) {
                        s_cand[q][slot][0] = A[i];
                        s_cand[q][slot][1] = B[i];
                        s_cand[q][slot][2] = r2;
                        s_cand[q][slot][3] = r3;
                    }
                }
            }
        }
    }
    __syncthreads();

    float bestd = FARF;
    int bestf = 0x7fffffff;

    const int n = s_cnt[qr];
    if (n <= CAPC) {
        // ---- render: 8-sliced scan of this region's list, 1 wave/candidate ----
        for (int i = slice; i < n; i += SLICES) {
            const float4 a = s_cand[qr][i][0];   // broadcast reads, conflict-free
            const float4 b = s_cand[qr][i][1];
            const float4 c = s_cand[qr][i][2];
            const float4 d = s_cand[qr][i][3];
            const float X0 = a.x, Y0 = a.y, Z0 = a.z, X1 = a.w;
            const float Y1 = b.x, Z1 = b.y, X2 = b.z, Y2 = b.w;
            const float Z2 = c.x;
            const int f = __float_as_int(c.y);
            const float w0 = __fsub_rn(__fmul_rn(__fsub_rn(yp, Y1), c.z),
                                       __fmul_rn(__fsub_rn(xp, X1), c.w));
            const float w1 = __fsub_rn(__fmul_rn(__fsub_rn(yp, Y2), d.x),
                                       __fmul_rn(__fsub_rn(xp, X2), d.y));
            const float w2 = __fsub_rn(__fmul_rn(__fsub_rn(yp, Y0), d.z),
                                       __fmul_rn(__fsub_rn(xp, X0), d.w));
            // Equivalent to reference inside&&(wsum>0) for DRAW_BACKSIDE=False.
            if ((w0 > 0.0f) && (w1 > 0.0f) && (w2 > 0.0f)) {
                const float wsum = __fadd_rn(__fadd_rn(w0, w1), w2);
                float denom = __fadd_rn(__fadd_rn(__fdiv_rn(w0, Z0), __fdiv_rn(w1, Z1)),
                                        __fdiv_rn(w2, Z2));
                denom = (fabsf(denom) > EPSF) ? denom : EPSF;
                const float zp = __fdiv_rn(wsum, denom);
                if ((zp > NEARF) && (zp < FARF)) {
                    if (zp < bestd || (zp == bestd && f < bestf)) {
                        bestd = zp;
                        bestf = f;
                    }
                }
            }
        }
    } else {
        // Overflow (never expected): test every face directly from global.
        // Conservative-cull equivalence keeps this exact.
        for (int i = slice; i < NF; i += SLICES) {
            const float* p = faces + (size_t)i * 9;
            const float X0 = p[0], Y0 = p[1], Z0 = p[2];
            const float X1 = p[3], Y1 = p[4], Z1 = p[5];
            const float X2 = p[6], Y2 = p[7], Z2 = p[8];
            const float w0 = __fsub_rn(__fmul_rn(__fsub_rn(yp, Y1), __fsub_rn(X2, X1)),
                                       __fmul_rn(__fsub_rn(xp, X1), __fsub_rn(Y2, Y1)));
            const float w1 = __fsub_rn(__fmul_rn(__fsub_rn(yp, Y2), __fsub_rn(X0, X2)),
                                       __fmul_rn(__fsub_rn(xp, X2), __fsub_rn(Y0, Y2)));
            const float w2 = __fsub_rn(__fmul_rn(__fsub_rn(yp, Y0), __fsub_rn(X1, X0)),
                                       __fmul_rn(__fsub_rn(xp, X0), __fsub_rn(Y1, Y0)));
            if ((w0 > 0.0f) && (w1 > 0.0f) && (w2 > 0.0f)) {
                const float wsum = __fadd_rn(__fadd_rn(w0, w1), w2);
                float denom = __fadd_rn(__fadd_rn(__fdiv_rn(w0, Z0), __fdiv_rn(w1, Z1)),
                                        __fdiv_rn(w2, Z2));
                denom = (fabsf(denom) > EPSF) ? denom : EPSF;
                const float zp = __fdiv_rn(wsum, denom);
                if ((zp > NEARF) && (zp < FARF)) {
                    if (zp < bestd || (zp == bestd && i < bestf)) {
                        bestd = zp;
                        bestf = i;
                    }
                }
            }
        }
    }

    // ---- merge 8 slices per pixel via packed min-key ----
    s_key[threadIdx.x] =
        ((unsigned long long)__float_as_uint(bestd) << 32) | (unsigned int)bestf;
    __syncthreads();
    if (threadIdx.x < 128) {
        const int mqr = (int)threadIdx.x >> 6;       // region
        const int ml = (int)threadIdx.x & 63;        // lane within region
        const int base = mqr * 512 + ml;
        unsigned long long k = s_key[base];
#pragma unroll
        for (int s = 1; s < SLICES; ++s) {
            const unsigned long long ks = s_key[base + 64 * s];
            k = ks < k ? ks : k;
        }
        const float dd = __uint_as_float((unsigned int)(k >> 32));
        const int fi = (int)(unsigned int)k;
        const int opx = tx0 + (ml & (TILE - 1));
        const int opy = ty0 + mqr * 4 + (ml >> 4);
        out[opy * S + opx] = (dd < FARF) ? fi : -1;
    }
}

extern "C" void kernel_launch(void* const* d_in, const int* in_sizes, int n_in,
                              void* d_out, int out_size, void* d_ws, size_t ws_size,
                              hipStream_t stream) {
    const float* faces = (const float*)d_in[0];
    int* out = (int*)d_out;
    hipLaunchKernelGGL(raster_tile, dim3(2 * (S / TILE) * (S / TILE)), dim3(NT), 0,
                       stream, faces, out);
}

// Round 13
// 25.187 us; speedup vs baseline: 1.8964x; 1.1048x over previous
//
#include <hip/hip_runtime.h>

#define S 256
#define NF 4096
#define TILE 16
#define HTILE 8            // half-tile: block = 16 wide x 8 tall
#define NT 1024            // 8 slices x 128 pixels
#define SLICES 8
#define CAPC 512           // candidate slots (avg ~40 used; overflow -> exact fallback)
#define NEARF 0.1f
#define FARF 100.0f
#define EPSF 1e-8f

// R8's winning structure (best of 10 variants: 512 half-tile blocks, 2/CU,
// 32 waves/CU, single shared cull, min-key merge) + the two micro-diets that
// R12 validated as exact:
//  - body test (w0>0 && w1>0 && w2>0) == reference inside&&(wsum>0) for
//    DRAW_BACKSIDE=False (all-same-sign analysis; nonzero |w| >= ~1e-10 so
//    no product-underflow divergence), wsum computed only on the hit path;
//  - cull edge deltas only in the hit branch (identical __fsub_rn ops to the
//    reference's per-pixel values -> bit-identical, hoisted once per record).
// Merge via (depth_bits<<32|face) min-key: order-independent, exact
// lowest-index tie-break -> atomic compaction order is irrelevant.
__global__ __launch_bounds__(NT, 8) void raster_tile(const float* __restrict__ faces,
                                                     int* __restrict__ out) {
    __shared__ float4 s_cand[CAPC][4];          // 32 KB
    __shared__ unsigned long long s_key[NT];    // 8 KB
    __shared__ int s_cnt;

    const int bx = blockIdx.x;
    const int tile = bx & 255;
    const int half = bx >> 8;
    const int tx0 = (tile & (S / TILE - 1)) * TILE;
    const int ty0 = (tile / (S / TILE)) * TILE + half * HTILE;

    const int pix = threadIdx.x & 127;           // 16 x 8 pixels
    const int slice = threadIdx.x >> 7;          // wave-uniform
    const int px = tx0 + (pix & (TILE - 1));
    const int py = ty0 + (pix >> 4);
    // (2i+1-256)/256: odd numerator / pow2 -> exact in fp32.
    const float xp = (2.0f * px + 1.0f - 256.0f) * (1.0f / 256.0f);
    const float yp = (2.0f * py + 1.0f - 256.0f) * (1.0f / 256.0f);

    // Half-tile pixel-center bounds with margin vs ulp-level boundary flips.
    const float cxlo = (2.0f * tx0 + 1.0f - 256.0f) * (1.0f / 256.0f) - 1e-5f;
    const float cxhi = (2.0f * (tx0 + TILE - 1) + 1.0f - 256.0f) * (1.0f / 256.0f) + 1e-5f;
    const float cylo = (2.0f * ty0 + 1.0f - 256.0f) * (1.0f / 256.0f) - 1e-5f;
    const float cyhi = (2.0f * (ty0 + HTILE - 1) + 1.0f - 256.0f) * (1.0f / 256.0f) + 1e-5f;

    if (threadIdx.x == 0) s_cnt = 0;
    __syncthreads();

    // ---- cull: 4096 faces, 2 batches of 2 faces/thread (low VGPR) ----
#pragma unroll
    for (int g = 0; g < 2; ++g) {
        float4 A[2], B[2];
        float Cz[2];
#pragma unroll
        for (int i = 0; i < 2; ++i) {
            const int f = g * 2048 + i * 1024 + (int)threadIdx.x;
            const float* p = faces + (size_t)f * 9;
            A[i] = *(const float4*)p;        // x0,y0,z0,x1
            B[i] = *(const float4*)(p + 4);  // y1,z1,x2,y2
            Cz[i] = p[8];                    // z2
        }
#pragma unroll
        for (int i = 0; i < 2; ++i) {
            const float x0 = A[i].x, y0 = A[i].y, x1 = A[i].w;
            const float y1 = B[i].x, x2 = B[i].z, y2 = B[i].w;
            const float bxmin = fminf(x0, fminf(x1, x2));
            const float bxmax = fmaxf(x0, fmaxf(x1, x2));
            const float bymin = fminf(y0, fminf(y1, y2));
            const float bymax = fmaxf(y0, fmaxf(y1, y2));
            bool hit = (bxmax >= cxlo) && (bxmin <= cxhi) &&
                       (bymax >= cylo) && (bymin <= cyhi);
            if (hit) {
                // 2*signed area fp32: |err| < 1.5e-6 << 1e-4 margin -> no pixel
                // whose fp32 w_sum>0 can be lost to this cull.
                const float a2 = __fsub_rn(
                    __fmul_rn(__fsub_rn(x1, x0), __fsub_rn(y2, y0)),
                    __fmul_rn(__fsub_rn(x2, x0), __fsub_rn(y1, y0)));
                hit = (a2 > -1e-4f);
            }
            if (hit) {
                const float dx21 = __fsub_rn(x2, x1), dy21 = __fsub_rn(y2, y1);
                const float dx02 = __fsub_rn(x0, x2), dy02 = __fsub_rn(y0, y2);
                const float dx10 = __fsub_rn(x1, x0), dy10 = __fsub_rn(y1, y0);
                const int f = g * 2048 + i * 1024 + (int)threadIdx.x;
                const int slot = atomicAdd(&s_cnt, 1);
                if (slot < CAPC) {
                    s_cand[slot][0] = A[i];
                    s_cand[slot][1] = B[i];
                    s_cand[slot][2] =
                        make_float4(Cz[i], __int_as_float(f), dx21, dy21);
                    s_cand[slot][3] = make_float4(dx02, dy02, dx10, dy10);
                }
            }
        }
    }
    __syncthreads();

    float bestd = FARF;
    int bestf = 0x7fffffff;

    const int n = s_cnt;
    if (n <= CAPC) {
        // ---- render: 8-sliced scan, deltas precomputed ----
        for (int i = slice; i < n; i += SLICES) {
            const float4 a = s_cand[i][0];   // broadcast reads, conflict-free
            const float4 b = s_cand[i][1];
            const float4 c = s_cand[i][2];
            const float4 d = s_cand[i][3];
            const float X0 = a.x, Y0 = a.y, Z0 = a.z, X1 = a.w;
            const float Y1 = b.x, Z1 = b.y, X2 = b.z, Y2 = b.w;
            const float Z2 = c.x;
            const int f = __float_as_int(c.y);
            const float w0 = __fsub_rn(__fmul_rn(__fsub_rn(yp, Y1), c.z),
                                       __fmul_rn(__fsub_rn(xp, X1), c.w));
            const float w1 = __fsub_rn(__fmul_rn(__fsub_rn(yp, Y2), d.x),
                                       __fmul_rn(__fsub_rn(xp, X2), d.y));
            const float w2 = __fsub_rn(__fmul_rn(__fsub_rn(yp, Y0), d.z),
                                       __fmul_rn(__fsub_rn(xp, X0), d.w));
            // == reference inside && (wsum>0) for DRAW_BACKSIDE=False.
            if ((w0 > 0.0f) && (w1 > 0.0f) && (w2 > 0.0f)) {
                const float wsum = __fadd_rn(__fadd_rn(w0, w1), w2);
                float denom = __fadd_rn(__fadd_rn(__fdiv_rn(w0, Z0), __fdiv_rn(w1, Z1)),
                                        __fdiv_rn(w2, Z2));
                denom = (fabsf(denom) > EPSF) ? denom : EPSF;
                const float zp = __fdiv_rn(wsum, denom);
                if ((zp > NEARF) && (zp < FARF)) {
                    if (zp < bestd || (zp == bestd && f < bestf)) {
                        bestd = zp;
                        bestf = f;
                    }
                }
            }
        }
    } else {
        // Overflow (never expected): test every face directly from global.
        // Conservative-cull equivalence keeps this exact.
        for (int i = slice; i < NF; i += SLICES) {
            const float* p = faces + (size_t)i * 9;
            const float X0 = p[0], Y0 = p[1], Z0 = p[2];
            const float X1 = p[3], Y1 = p[4], Z1 = p[5];
            const float X2 = p[6], Y2 = p[7], Z2 = p[8];
            const float w0 = __fsub_rn(__fmul_rn(__fsub_rn(yp, Y1), __fsub_rn(X2, X1)),
                                       __fmul_rn(__fsub_rn(xp, X1), __fsub_rn(Y2, Y1)));
            const float w1 = __fsub_rn(__fmul_rn(__fsub_rn(yp, Y2), __fsub_rn(X0, X2)),
                                       __fmul_rn(__fsub_rn(xp, X2), __fsub_rn(Y0, Y2)));
            const float w2 = __fsub_rn(__fmul_rn(__fsub_rn(yp, Y0), __fsub_rn(X1, X0)),
                                       __fmul_rn(__fsub_rn(xp, X0), __fsub_rn(Y1, Y0)));
            if ((w0 > 0.0f) && (w1 > 0.0f) && (w2 > 0.0f)) {
                const float wsum = __fadd_rn(__fadd_rn(w0, w1), w2);
                float denom = __fadd_rn(__fadd_rn(__fdiv_rn(w0, Z0), __fdiv_rn(w1, Z1)),
                                        __fdiv_rn(w2, Z2));
                denom = (fabsf(denom) > EPSF) ? denom : EPSF;
                const float zp = __fdiv_rn(wsum, denom);
                if ((zp > NEARF) && (zp < FARF)) {
                    if (zp < bestd || (zp == bestd && i < bestf)) {
                        bestd = zp;
                        bestf = i;
                    }
                }
            }
        }
    }

    // ---- merge 8 slices per pixel via packed min-key ----
    s_key[threadIdx.x] =
        ((unsigned long long)__float_as_uint(bestd) << 32) | (unsigned int)bestf;
    __syncthreads();
    if (threadIdx.x < 128) {
        unsigned long long k = s_key[threadIdx.x];
#pragma unroll
        for (int s = 1; s < SLICES; ++s) {
            const unsigned long long ks = s_key[threadIdx.x + 128 * s];
            k = ks < k ? ks : k;
        }
        const float dd = __uint_as_float((unsigned int)(k >> 32));
        const int fi = (int)(unsigned int)k;
        const int opx = tx0 + ((int)threadIdx.x & (TILE - 1));
        const int opy = ty0 + ((int)threadIdx.x >> 4);
        out[opy * S + opx] = (dd < FARF) ? fi : -1;
    }
}

extern "C" void kernel_launch(void* const* d_in, const int* in_sizes, int n_in,
                              void* d_out, int out_size, void* d_ws, size_t ws_size,
                              hipStream_t stream) {
    const float* faces = (const float*)d_in[0];
    int* out = (int*)d_out;
    hipLaunchKernelGGL(raster_tile, dim3(2 * (S / TILE) * (S / TILE)), dim3(NT), 0,
                       stream, faces, out);
}